// Round 1
// baseline (207.341 us; speedup 1.0000x reference)
//
#include <hip/hip_runtime.h>

#define BN_EPS 1e-5f

typedef short bf16x8 __attribute__((ext_vector_type(8)));
typedef float f32x4  __attribute__((ext_vector_type(4)));

static __device__ __forceinline__ unsigned short f2bf(float f) {
    union { float f; unsigned int u; } v; v.f = f;
    unsigned int u = v.u;
    unsigned int r = (u + 0x7FFFu + ((u >> 16) & 1u)) >> 16;   // round-to-nearest-even
    return (unsigned short)r;
}

// ---------------- prep kernels ----------------

// h (fp32) -> hb (bf16), 4 elems/thread
__global__ void k_cvt_h(const float* __restrict__ h, unsigned short* __restrict__ hb, int n4) {
    int i = blockIdx.x * blockDim.x + threadIdx.x;
    if (i < n4) {
        float4 f = ((const float4*)h)[i];
        ushort4 o;
        o.x = f2bf(f.x); o.y = f2bf(f.y); o.z = f2bf(f.z); o.w = f2bf(f.w);
        ((ushort4*)hb)[i] = o;
    }
}

// W0 [128][256] -> frag-linear bf16 W0sw[kb(8)][nt(8)][lane(64)][j(8)], BN0 scale folded
__global__ void k_w0sw(const float* __restrict__ W0, const float* __restrict__ g0,
                       const float* __restrict__ v0, unsigned short* __restrict__ W0sw) {
    int t = blockIdx.x * 256 + threadIdx.x;           // < 32768
    if (t >= 32768) return;
    int j = t & 7, lane = (t >> 3) & 63, nt = (t >> 9) & 7, kb = t >> 12;
    int k = kb * 32 + (lane >> 4) * 8 + j;            // 0..255
    int n = nt * 16 + (lane & 15);                    // 0..127
    float s = g0[k] * rsqrtf(v0[k] + BN_EPS);
    W0sw[t] = f2bf(W0[n * 256 + k] * s);
}

// W1 [128][128] -> frag-linear bf16 W1sw[kb(4)][nt(8)][lane(64)][j(8)], BN1 scale folded
__global__ void k_w1sw(const float* __restrict__ W1, const float* __restrict__ g1,
                       const float* __restrict__ v1, unsigned short* __restrict__ W1sw) {
    int t = blockIdx.x * 256 + threadIdx.x;           // < 16384
    if (t >= 16384) return;
    int j = t & 7, lane = (t >> 3) & 63, nt = (t >> 9) & 7, kb = t >> 12;
    int k = kb * 32 + (lane >> 4) * 8 + j;            // 0..127
    int n = nt * 16 + (lane & 15);                    // 0..127
    float s = g1[k] * rsqrtf(v1[k] + BN_EPS);
    W1sw[t] = f2bf(W1[n * 128 + k] * s);
}

// folded biases + stage-2 weights (one block, 128 threads)
__global__ void k_bias(const float* __restrict__ W0, const float* __restrict__ b0,
                       const float* __restrict__ W1, const float* __restrict__ b1,
                       const float* __restrict__ W2, const float* __restrict__ b2,
                       const float* __restrict__ g0, const float* __restrict__ be0,
                       const float* __restrict__ m0, const float* __restrict__ v0,
                       const float* __restrict__ g1, const float* __restrict__ be1,
                       const float* __restrict__ m1, const float* __restrict__ v1,
                       const float* __restrict__ g2, const float* __restrict__ be2,
                       const float* __restrict__ m2, const float* __restrict__ v2,
                       float* __restrict__ b0f, float* __restrict__ b1f,
                       float* __restrict__ w2f, float* __restrict__ b2f) {
    int t = threadIdx.x;
    if (t < 128) {
        float s = 0.f;
        for (int k = 0; k < 256; k++) {
            float sc = g0[k] * rsqrtf(v0[k] + BN_EPS);
            float tk = be0[k] - m0[k] * sc;
            s += W0[t * 256 + k] * tk;
        }
        b0f[t] = b0[t] + s;
        float s1 = 0.f;
        for (int k = 0; k < 128; k++) {
            float sc = g1[k] * rsqrtf(v1[k] + BN_EPS);
            float tk = be1[k] - m1[k] * sc;
            s1 += W1[t * 128 + k] * tk;
        }
        b1f[t] = b1[t] + s1;
        float sc2 = g2[t] * rsqrtf(v2[t] + BN_EPS);
        w2f[t] = W2[t] * sc2;
        if (t == 0) {
            float s2 = 0.f;
            for (int k = 0; k < 128; k++) {
                float sc = g2[k] * rsqrtf(v2[k] + BN_EPS);
                float tk = be2[k] - m2[k] * sc;
                s2 += W2[k] * tk;
            }
            b2f[0] = b2[0] + s2;
        }
    }
}

// ---------------- main fused kernel ----------------
// block = 256 threads = 4 waves; 16 edges/wave, 64 edges/block.
// Stage0: A = gathered [16 x 256] bf16 (direct global, L2-resident hb),
//         B = W0sw frag-linear; 8 kb x 8 nt MFMAs (16x16x32).
// Stage1: A = relu(x0+b0) round-tripped through LDS (C-layout -> A-layout),
//         B = W1sw; 4 kb x 8 nt MFMAs.
// Stage2: fp32 dot with w2f, shuffle-reduce over 16 lanes, float4 store.
__global__ __launch_bounds__(256) void k_main(
        const int* __restrict__ src, const int* __restrict__ dst,
        const unsigned short* __restrict__ hb,
        const unsigned short* __restrict__ W0sw, const unsigned short* __restrict__ W1sw,
        const float* __restrict__ b0f, const float* __restrict__ b1f,
        const float* __restrict__ w2f, const float* __restrict__ b2fp,
        float* __restrict__ out, int E) {
    __shared__ int rowsS[4][2][16];
    __shared__ __align__(16) unsigned short x1S[4][16 * 128];

    const int tid  = threadIdx.x;
    const int wave = tid >> 6;
    const int lane = tid & 63;
    const int quad = lane >> 4;
    const int m    = lane & 15;
    const int eBase = blockIdx.x * 64 + wave * 16;

    if (lane < 32) {
        int half = lane >> 4, idx = lane & 15;
        int e = eBase + idx;
        if (e >= E) e = E - 1;
        rowsS[wave][half][idx] = half ? dst[e] : src[e];
    }
    __syncthreads();

    const int rS = rowsS[wave][0][m];
    const int rD = rowsS[wave][1][m];

    float b0v[8], b1v[8], w2v[8];
#pragma unroll
    for (int nt = 0; nt < 8; nt++) {
        b0v[nt] = b0f[nt * 16 + m];
        b1v[nt] = b1f[nt * 16 + m];
        w2v[nt] = w2f[nt * 16 + m];
    }
    const float b2s = *b2fp;

    // ---- stage 0 ----
    f32x4 acc[8];
#pragma unroll
    for (int nt = 0; nt < 8; nt++) acc[nt] = (f32x4){0.f, 0.f, 0.f, 0.f};

#pragma unroll
    for (int kb = 0; kb < 8; kb++) {
        int row = (kb < 4) ? rS : rD;
        const unsigned short* ap = hb + row * 128 + (kb & 3) * 32 + quad * 8;
        bf16x8 a = *(const bf16x8*)ap;
#pragma unroll
        for (int nt = 0; nt < 8; nt++) {
            bf16x8 b = *(const bf16x8*)(W0sw + ((kb * 8 + nt) * 64 + lane) * 8);
            acc[nt] = __builtin_amdgcn_mfma_f32_16x16x32_bf16(a, b, acc[nt], 0, 0, 0);
        }
    }

    // ---- relu(x0 + b0') -> bf16 tile in LDS (row-major [m][n]) ----
    unsigned short* xw = &x1S[wave][0];
#pragma unroll
    for (int nt = 0; nt < 8; nt++) {
#pragma unroll
        for (int r = 0; r < 4; r++) {
            float v = acc[nt][r] + b0v[nt];
            v = v > 0.f ? v : 0.f;
            xw[(quad * 4 + r) * 128 + nt * 16 + m] = f2bf(v);
        }
    }

    // ---- stage 1 ----
    f32x4 acc1[8];
#pragma unroll
    for (int nt = 0; nt < 8; nt++) acc1[nt] = (f32x4){0.f, 0.f, 0.f, 0.f};

#pragma unroll
    for (int kb = 0; kb < 4; kb++) {
        bf16x8 a = *(const bf16x8*)(xw + m * 128 + kb * 32 + quad * 8);
#pragma unroll
        for (int nt = 0; nt < 8; nt++) {
            bf16x8 b = *(const bf16x8*)(W1sw + ((kb * 8 + nt) * 64 + lane) * 8);
            acc1[nt] = __builtin_amdgcn_mfma_f32_16x16x32_bf16(a, b, acc1[nt], 0, 0, 0);
        }
    }

    // ---- stage 2: out[e] = sum_n relu(x1[e][n] + b1'[n]) * w2'[n] + b2' ----
    float s[4] = {0.f, 0.f, 0.f, 0.f};
#pragma unroll
    for (int nt = 0; nt < 8; nt++) {
#pragma unroll
        for (int r = 0; r < 4; r++) {
            float v = acc1[nt][r] + b1v[nt];
            v = v > 0.f ? v : 0.f;
            s[r] += v * w2v[nt];
        }
    }
#pragma unroll
    for (int off = 1; off < 16; off <<= 1) {
#pragma unroll
        for (int r = 0; r < 4; r++) s[r] += __shfl_xor(s[r], off, 16);
    }
    if (m == 0) {
        int e0 = eBase + quad * 4;
        if (e0 + 3 < E) {
            float4 o;
            o.x = s[0] + b2s; o.y = s[1] + b2s; o.z = s[2] + b2s; o.w = s[3] + b2s;
            *(float4*)(out + e0) = o;
        } else {
#pragma unroll
            for (int r = 0; r < 4; r++)
                if (e0 + r < E) out[e0 + r] = s[r] + b2s;
        }
    }
}

// ---------------- launcher ----------------
extern "C" void kernel_launch(void* const* d_in, const int* in_sizes, int n_in,
                              void* d_out, int out_size, void* d_ws, size_t ws_size,
                              hipStream_t stream) {
    const float* h   = (const float*)d_in[0];
    const int*   src = (const int*)d_in[1];
    const int*   dst = (const int*)d_in[2];
    const float* W0  = (const float*)d_in[3];
    const float* b0  = (const float*)d_in[4];
    const float* W1  = (const float*)d_in[5];
    const float* b1  = (const float*)d_in[6];
    const float* W2  = (const float*)d_in[7];
    const float* b2  = (const float*)d_in[8];
    const float* g0  = (const float*)d_in[9];
    const float* be0 = (const float*)d_in[10];
    const float* g1  = (const float*)d_in[11];
    const float* be1 = (const float*)d_in[12];
    const float* g2  = (const float*)d_in[13];
    const float* be2 = (const float*)d_in[14];
    const float* m0  = (const float*)d_in[15];
    const float* v0  = (const float*)d_in[16];
    const float* m1  = (const float*)d_in[17];
    const float* v1  = (const float*)d_in[18];
    const float* m2  = (const float*)d_in[19];
    const float* v2  = (const float*)d_in[20];
    float* out = (float*)d_out;

    const int hsz = in_sizes[0];          // N*128
    const int E   = in_sizes[1];

    char* ws = (char*)d_ws;
    size_t off = (size_t)hsz * 2;         // hb bytes
    off = (off + 255) & ~(size_t)255;
    unsigned short* hb   = (unsigned short*)ws;
    unsigned short* W0sw = (unsigned short*)(ws + off);  off += 65536;
    unsigned short* W1sw = (unsigned short*)(ws + off);  off += 32768;
    float* b0f = (float*)(ws + off);  off += 512;
    float* b1f = (float*)(ws + off);  off += 512;
    float* w2f = (float*)(ws + off);  off += 512;
    float* b2f = (float*)(ws + off);  off += 16;

    int n4 = hsz / 4;
    k_cvt_h<<<(n4 + 255) / 256, 256, 0, stream>>>(h, hb, n4);
    k_w0sw<<<128, 256, 0, stream>>>(W0, g0, v0, W0sw);
    k_w1sw<<<64, 256, 0, stream>>>(W1, g1, v1, W1sw);
    k_bias<<<1, 128, 0, stream>>>(W0, b0, W1, b1, W2, b2,
                                  g0, be0, m0, v0, g1, be1, m1, v1, g2, be2, m2, v2,
                                  b0f, b1f, w2f, b2f);

    int nBlocks = (E + 63) / 64;
    k_main<<<nBlocks, 256, 0, stream>>>(src, dst, hb, W0sw, W1sw,
                                        b0f, b1f, w2f, b2f, out, E);
}

// Round 3
// 174.810 us; speedup vs baseline: 1.1861x; 1.1861x over previous
//
#include <hip/hip_runtime.h>

#define BN_EPS 1e-5f

typedef short bf16x8 __attribute__((ext_vector_type(8)));
typedef float f32x4  __attribute__((ext_vector_type(4)));

static __device__ __forceinline__ unsigned short f2bf(float f) {
    union { float f; unsigned int u; } v; v.f = f;
    unsigned int u = v.u;
    unsigned int r = (u + 0x7FFFu + ((u >> 16) & 1u)) >> 16;   // round-to-nearest-even
    return (unsigned short)r;
}

// ---------------- prep kernels ----------------

// h (fp32) -> hb (bf16), 4 elems/thread
__global__ void k_cvt_h(const float* __restrict__ h, unsigned short* __restrict__ hb, int n4) {
    int i = blockIdx.x * blockDim.x + threadIdx.x;
    if (i < n4) {
        float4 f = ((const float4*)h)[i];
        ushort4 o;
        o.x = f2bf(f.x); o.y = f2bf(f.y); o.z = f2bf(f.z); o.w = f2bf(f.w);
        ((ushort4*)hb)[i] = o;
    }
}

// W0 [128][256] -> frag-linear bf16 W0sw[kb(8)][nt(8)][lane(64)][j(8)], BN0 scale folded
__global__ void k_w0sw(const float* __restrict__ W0, const float* __restrict__ g0,
                       const float* __restrict__ v0, unsigned short* __restrict__ W0sw) {
    int t = blockIdx.x * 256 + threadIdx.x;           // < 32768
    if (t >= 32768) return;
    int j = t & 7, lane = (t >> 3) & 63, nt = (t >> 9) & 7, kb = t >> 12;
    int k = kb * 32 + (lane >> 4) * 8 + j;            // 0..255
    int n = nt * 16 + (lane & 15);                    // 0..127
    float s = g0[k] * rsqrtf(v0[k] + BN_EPS);
    W0sw[t] = f2bf(W0[n * 256 + k] * s);
}

// W1 [128][128] -> frag-linear bf16 W1sw[kb(4)][nt(8)][lane(64)][j(8)], BN1 scale folded
__global__ void k_w1sw(const float* __restrict__ W1, const float* __restrict__ g1,
                       const float* __restrict__ v1, unsigned short* __restrict__ W1sw) {
    int t = blockIdx.x * 256 + threadIdx.x;           // < 16384
    if (t >= 16384) return;
    int j = t & 7, lane = (t >> 3) & 63, nt = (t >> 9) & 7, kb = t >> 12;
    int k = kb * 32 + (lane >> 4) * 8 + j;            // 0..127
    int n = nt * 16 + (lane & 15);                    // 0..127
    float s = g1[k] * rsqrtf(v1[k] + BN_EPS);
    W1sw[t] = f2bf(W1[n * 128 + k] * s);
}

// folded biases + stage-2 weights — PARALLEL version.
// grid = 128 blocks x 64 threads (1 wave). Block i:
//   b0f[i] = b0[i] + sum_k W0[i][k] * t0[k]      (coalesced row read)
//   b1f[i] = b1[i] + sum_k W1[i][k] * t1[k]
//   w2f[i] = W2[i] * s2[i]
//   block 0 additionally: b2f = b2 + sum_k W2[k] * t2[k]
__global__ __launch_bounds__(64) void k_bias(
        const float* __restrict__ W0, const float* __restrict__ b0,
        const float* __restrict__ W1, const float* __restrict__ b1,
        const float* __restrict__ W2, const float* __restrict__ b2,
        const float* __restrict__ g0, const float* __restrict__ be0,
        const float* __restrict__ m0, const float* __restrict__ v0,
        const float* __restrict__ g1, const float* __restrict__ be1,
        const float* __restrict__ m1, const float* __restrict__ v1,
        const float* __restrict__ g2, const float* __restrict__ be2,
        const float* __restrict__ m2, const float* __restrict__ v2,
        float* __restrict__ b0f, float* __restrict__ b1f,
        float* __restrict__ w2f, float* __restrict__ b2f) {
    const int i    = blockIdx.x;      // output row 0..127
    const int lane = threadIdx.x;     // 0..63

    float s0 = 0.f;
#pragma unroll
    for (int c = 0; c < 4; c++) {
        int k = c * 64 + lane;
        float sc = g0[k] * rsqrtf(v0[k] + BN_EPS);
        float tk = be0[k] - m0[k] * sc;
        s0 += W0[i * 256 + k] * tk;
    }
    float s1 = 0.f;
#pragma unroll
    for (int c = 0; c < 2; c++) {
        int k = c * 64 + lane;
        float sc = g1[k] * rsqrtf(v1[k] + BN_EPS);
        float tk = be1[k] - m1[k] * sc;
        s1 += W1[i * 128 + k] * tk;
    }
    float s2 = 0.f;
    if (i == 0) {
#pragma unroll
        for (int c = 0; c < 2; c++) {
            int k = c * 64 + lane;
            float sc = g2[k] * rsqrtf(v2[k] + BN_EPS);
            float tk = be2[k] - m2[k] * sc;
            s2 += W2[k] * tk;
        }
    }
#pragma unroll
    for (int off = 1; off < 64; off <<= 1) {
        s0 += __shfl_xor(s0, off);
        s1 += __shfl_xor(s1, off);
        s2 += __shfl_xor(s2, off);
    }
    if (lane == 0) {
        b0f[i] = b0[i] + s0;
        b1f[i] = b1[i] + s1;
        w2f[i] = W2[i] * (g2[i] * rsqrtf(v2[i] + BN_EPS));
        if (i == 0) b2f[0] = b2[0] + s2;
    }
}

// ---------------- main fused kernel ----------------
// block = 256 threads = 4 waves; 64 edges/wave (M4-blocked), 256 edges/block.
// Stage0: A = 4 gathered 16-edge groups (global, L2-resident hb),
//         B = W0sw frag-linear; each B-frag load feeds 4 MFMAs (16x16x32).
// x1 round-trip: epilogue writes relu(x0+b0') into LDS directly in stage-1
//         A-fragment order ("frag-linear"), so stage-1 A ds_read_b128 is
//         lane-consecutive 16B = bank-conflict-free. Per-wave buffer: no
//         __syncthreads needed (compiler inserts lgkmcnt).
// Stage1: B = W1sw frag-linear, 4 MFMAs per B-load.
// Stage2: fp32 dot with w2f, 16-lane shuffle reduce, float4 store.
__global__ __launch_bounds__(256, 2) void k_main(
        const int* __restrict__ src, const int* __restrict__ dst,
        const unsigned short* __restrict__ hb,
        const unsigned short* __restrict__ W0sw, const unsigned short* __restrict__ W1sw,
        const float* __restrict__ b0f, const float* __restrict__ b1f,
        const float* __restrict__ w2f, const float* __restrict__ b2fp,
        float* __restrict__ out, int E) {
    // x1S: [wave(4)][g(4)][kb1(4)][lane(64)][j(8)] bf16 = 64 KB exactly
    __shared__ __align__(16) unsigned short x1S[4 * 4 * 4 * 64 * 8];

    const int tid  = threadIdx.x;
    const int wave = tid >> 6;
    const int lane = tid & 63;
    const int quad = lane >> 4;
    const int m    = lane & 15;
    const int eBase = blockIdx.x * 256 + wave * 64;

    // gather rows for 4 m-groups (lanes duplicate across quads; L1/L2 broadcast)
    int rS[4], rD[4];
#pragma unroll
    for (int g = 0; g < 4; g++) {
        int e = eBase + g * 16 + m;
        if (e >= E) e = E - 1;
        rS[g] = src[e];
        rD[g] = dst[e];
    }

    float b0v[8], b1v[8], w2v[8];
#pragma unroll
    for (int nt = 0; nt < 8; nt++) {
        b0v[nt] = b0f[nt * 16 + m];
        b1v[nt] = b1f[nt * 16 + m];
        w2v[nt] = w2f[nt * 16 + m];
    }
    const float b2s = *b2fp;

    // ---- stage 0: [64 x 256] @ [256 x 128] ----
    f32x4 acc0[4][8];
#pragma unroll
    for (int g = 0; g < 4; g++)
#pragma unroll
        for (int nt = 0; nt < 8; nt++) acc0[g][nt] = (f32x4){0.f, 0.f, 0.f, 0.f};

#pragma unroll
    for (int kb = 0; kb < 8; kb++) {
        bf16x8 a[4];
#pragma unroll
        for (int g = 0; g < 4; g++) {
            int row = (kb < 4) ? rS[g] : rD[g];
            a[g] = *(const bf16x8*)(hb + row * 128 + (kb & 3) * 32 + quad * 8);
        }
#pragma unroll
        for (int nt = 0; nt < 8; nt++) {
            bf16x8 b = *(const bf16x8*)(W0sw + ((kb * 8 + nt) * 64 + lane) * 8);
#pragma unroll
            for (int g = 0; g < 4; g++)
                acc0[g][nt] = __builtin_amdgcn_mfma_f32_16x16x32_bf16(a[g], b, acc0[g][nt], 0, 0, 0);
        }
    }

    // ---- epilogue 0: relu(x0 + b0') -> x1S in stage-1 A-frag order ----
    // value at (edge_local = quad*4+r, n = nt*16+m) goes to stage-1 frag coords:
    //   kb1 = nt>>1, koff = (nt&1)*16+m, quad' = koff>>3, j = koff&7,
    //   lane' = quad'*16 + edge_local
#pragma unroll
    for (int g = 0; g < 4; g++) {
#pragma unroll
        for (int nt = 0; nt < 8; nt++) {
            int kb1 = nt >> 1;
            int qp  = ((nt & 1) << 1) | (m >> 3);
            int j   = m & 7;
            unsigned short* base = x1S + (((wave * 16 + g * 4 + kb1) * 64) + qp * 16 + quad * 4) * 8 + j;
#pragma unroll
            for (int r = 0; r < 4; r++) {
                float v = acc0[g][nt][r] + b0v[nt];
                v = v > 0.f ? v : 0.f;
                base[r * 8] = f2bf(v);
            }
        }
    }

    // ---- stage 1: [64 x 128] @ [128 x 128] ----
    f32x4 acc1[4][8];
#pragma unroll
    for (int g = 0; g < 4; g++)
#pragma unroll
        for (int nt = 0; nt < 8; nt++) acc1[g][nt] = (f32x4){0.f, 0.f, 0.f, 0.f};

#pragma unroll
    for (int kb = 0; kb < 4; kb++) {
        bf16x8 a[4];
#pragma unroll
        for (int g = 0; g < 4; g++)
            a[g] = *(const bf16x8*)(x1S + ((wave * 16 + g * 4 + kb) * 64 + lane) * 8);
#pragma unroll
        for (int nt = 0; nt < 8; nt++) {
            bf16x8 b = *(const bf16x8*)(W1sw + ((kb * 8 + nt) * 64 + lane) * 8);
#pragma unroll
            for (int g = 0; g < 4; g++)
                acc1[g][nt] = __builtin_amdgcn_mfma_f32_16x16x32_bf16(a[g], b, acc1[g][nt], 0, 0, 0);
        }
    }

    // ---- stage 2: out[e] = sum_n relu(x1[e][n] + b1'[n]) * w2'[n] + b2' ----
#pragma unroll
    for (int g = 0; g < 4; g++) {
        float s[4] = {0.f, 0.f, 0.f, 0.f};
#pragma unroll
        for (int nt = 0; nt < 8; nt++) {
#pragma unroll
            for (int r = 0; r < 4; r++) {
                float v = acc1[g][nt][r] + b1v[nt];
                v = v > 0.f ? v : 0.f;
                s[r] += v * w2v[nt];
            }
        }
#pragma unroll
        for (int off = 1; off < 16; off <<= 1) {
#pragma unroll
            for (int r = 0; r < 4; r++) s[r] += __shfl_xor(s[r], off, 16);
        }
        if (m == 0) {
            int e0 = eBase + g * 16 + quad * 4;
            if (e0 + 3 < E) {
                float4 o;
                o.x = s[0] + b2s; o.y = s[1] + b2s; o.z = s[2] + b2s; o.w = s[3] + b2s;
                *(float4*)(out + e0) = o;
            } else {
#pragma unroll
                for (int r = 0; r < 4; r++)
                    if (e0 + r < E) out[e0 + r] = s[r] + b2s;
            }
        }
    }
}

// ---------------- launcher ----------------
extern "C" void kernel_launch(void* const* d_in, const int* in_sizes, int n_in,
                              void* d_out, int out_size, void* d_ws, size_t ws_size,
                              hipStream_t stream) {
    const float* h   = (const float*)d_in[0];
    const int*   src = (const int*)d_in[1];
    const int*   dst = (const int*)d_in[2];
    const float* W0  = (const float*)d_in[3];
    const float* b0  = (const float*)d_in[4];
    const float* W1  = (const float*)d_in[5];
    const float* b1  = (const float*)d_in[6];
    const float* W2  = (const float*)d_in[7];
    const float* b2  = (const float*)d_in[8];
    const float* g0  = (const float*)d_in[9];
    const float* be0 = (const float*)d_in[10];
    const float* g1  = (const float*)d_in[11];
    const float* be1 = (const float*)d_in[12];
    const float* g2  = (const float*)d_in[13];
    const float* be2 = (const float*)d_in[14];
    const float* m0  = (const float*)d_in[15];
    const float* v0  = (const float*)d_in[16];
    const float* m1  = (const float*)d_in[17];
    const float* v1  = (const float*)d_in[18];
    const float* m2  = (const float*)d_in[19];
    const float* v2  = (const float*)d_in[20];
    float* out = (float*)d_out;

    const int hsz = in_sizes[0];          // N*128
    const int E   = in_sizes[1];

    char* ws = (char*)d_ws;
    size_t off = (size_t)hsz * 2;         // hb bytes
    off = (off + 255) & ~(size_t)255;
    unsigned short* hb   = (unsigned short*)ws;
    unsigned short* W0sw = (unsigned short*)(ws + off);  off += 65536;
    unsigned short* W1sw = (unsigned short*)(ws + off);  off += 32768;
    float* b0f = (float*)(ws + off);  off += 512;
    float* b1f = (float*)(ws + off);  off += 512;
    float* w2f = (float*)(ws + off);  off += 512;
    float* b2f = (float*)(ws + off);  off += 16;

    int n4 = hsz / 4;
    k_cvt_h<<<(n4 + 255) / 256, 256, 0, stream>>>(h, hb, n4);
    k_w0sw<<<128, 256, 0, stream>>>(W0, g0, v0, W0sw);
    k_w1sw<<<64, 256, 0, stream>>>(W1, g1, v1, W1sw);
    k_bias<<<128, 64, 0, stream>>>(W0, b0, W1, b1, W2, b2,
                                   g0, be0, m0, v0, g1, be1, m1, v1, g2, be2, m2, v2,
                                   b0f, b1f, w2f, b2f);

    int nBlocks = (E + 255) / 256;
    k_main<<<nBlocks, 256, 0, stream>>>(src, dst, hb, W0sw, W1sw,
                                        b0f, b1f, w2f, b2f, out, E);
}